// Round 3
// baseline (598.243 us; speedup 1.0000x reference)
//
#include <hip/hip_runtime.h>
#include <hip/hip_bf16.h>

#define N_NODES 4096
#define N_EDGES 8192
#define NGRAPH  256
#define AFEAT   9
#define BFEAT   4
#define H       128
#define NL      3
#define KS      129              // k-slices including the e2_b bias slice
#define SPLITS  8
#define SLICE_SH    16384        // shorts per k-slice (chunked layout)
#define SLICE_BYTES 32768        // bytes per k-slice

typedef short short8 __attribute__((ext_vector_type(8)));
typedef short short4v __attribute__((ext_vector_type(4)));
typedef float f32x4 __attribute__((ext_vector_type(4)));

// ---- bf16 helpers (RNE, finite inputs) ----
__device__ __forceinline__ short f2b(float f){
    union { float f; unsigned u; } c; c.f = f;
    unsigned r = c.u + 0x7FFFu + ((c.u >> 16) & 1u);
    return (short)(r >> 16);
}
__device__ __forceinline__ float b2f(short b){
    union { unsigned u; float f; } c;
    c.u = ((unsigned)(unsigned short)b) << 16;
    return c.f;
}
__device__ __forceinline__ float gelu_exact(float x){
    return 0.5f * x * (1.0f + erff(x * 0.70710678118654752440f));
}
__device__ __forceinline__ void async_copy16(const void* g, void* l){
    typedef __attribute__((address_space(1))) const char AS1C;
    typedef __attribute__((address_space(3))) char AS3;
    __builtin_amdgcn_global_load_lds((AS1C*)g, (AS3*)l, 16, 0, 0);
}

// ---------- K0: e2_w/e2_b -> bt[l][k] in fragment-chunk order ----------
// Element B_k[i][o] stored at short offset
// ((((o>>4)*4 + (i>>5))*16 + (o&15))*4 + ((i>>3)&3))*8 + (i&7).
// For fixed (o-tile t, ic): a wave's 64 lanes (col=o&15, quad) read one
// contiguous aligned 1 KB line (byte off (t*4+ic)*1024 + col*64 + quad*16).
__global__ void k_prep_b(const float* __restrict__ e2w, const float* __restrict__ e2b,
                         short* __restrict__ bt){
    __shared__ float ts[H][33];
    int b  = blockIdx.x;
    int o0 = (b & 3) * 32;
    int k  = (b >> 2) % KS;
    int l  = (b >> 2) / KS;
    const float* src = (k < H) ? (e2w + ((size_t)l * H + k) * (H * H))
                               : (e2b + (size_t)l * (H * H));
    for (int idx = threadIdx.x; idx < H * 32; idx += 256){
        int i = idx >> 5, op = idx & 31;
        ts[i][op] = src[i * H + o0 + op];
    }
    __syncthreads();
    short* dst = bt + (size_t)(l * KS + k) * SLICE_SH;
    for (int idx = threadIdx.x; idx < 32 * H; idx += 256){
        int j    = idx & 7;
        int quad = (idx >> 3) & 3;
        int op   = (idx >> 5) & 31;
        int ic   = idx >> 10;
        int i    = ic * 32 + quad * 8 + j;
        int o    = o0 + op;
        dst[((((o >> 4) * 4 + ic) * 16 + (o & 15)) * 4 + quad) * 8 + j] = f2b(ts[i][op]);
    }
}

// ---------- K1: h0 = relu(x @ atom_w + atom_b) ----------
__global__ void k_atom(const float* __restrict__ x, const float* __restrict__ aw,
                       const float* __restrict__ ab, float* __restrict__ h,
                       short* __restrict__ hb){
    __shared__ float xs[AFEAT];
    int n = blockIdx.x, o = threadIdx.x;
    if (o < AFEAT) xs[o] = x[n * AFEAT + o];
    __syncthreads();
    float a = ab[o];
    #pragma unroll
    for (int f = 0; f < AFEAT; ++f) a += xs[f] * aw[f * H + o];
    a = fmaxf(a, 0.0f);
    h[(size_t)n * H + o]  = a;
    hb[(size_t)n * H + o] = f2b(a);
}

// ---------- K2: in-degree ----------
__global__ void k_deg(const int* __restrict__ ei, float* __restrict__ deg){
    int e = blockIdx.x * 256 + threadIdx.x;
    if (e < N_EDGES) atomicAdd(&deg[ei[N_EDGES + e]], 1.0f);
}

// ---------- K3: eh = gelu(edge_attr @ e1_w + e1_b), transposed to [k][e] bf16 ----------
__global__ void k_edge_mlp(const float* __restrict__ ea, const float* __restrict__ w1,
                           const float* __restrict__ b1, short* __restrict__ ehT, int l){
    __shared__ float as[BFEAT];
    int e = blockIdx.x, o = threadIdx.x;
    if (o < BFEAT) as[o] = ea[e * BFEAT + o];
    __syncthreads();
    float v = b1[l * H + o];
    #pragma unroll
    for (int f = 0; f < BFEAT; ++f) v += as[f] * w1[(l * BFEAT + f) * H + o];
    v = gelu_exact(v);
    ehT[(size_t)o * N_EDGES + e] = f2b(v);
    if (o == 0) ehT[(size_t)H * N_EDGES + e] = f2b(1.0f);   // bias slice
}

// ---------- K4: the big fused GEMM: parts[split][e][o] = sum_k eh[e,k]*(g[e] @ B_k) ----------
// 8 waves (2 e-halves x 4 col-quarters), LDS double-buffered B slices with
// counted-vmcnt prefetch; 2 blocks/CU -> 4 waves/SIMD for latency hiding.
__global__ __launch_bounds__(512, 4)
void k_msg_gemm(const short* __restrict__ bt, const short* __restrict__ ehT,
                const short* __restrict__ hb, const int* __restrict__ ei,
                float* __restrict__ parts, int l){
    __shared__ __align__(16) char smem[2 * SLICE_BYTES + 17 * H * 2];
    short* ehs = (short*)(smem + 2 * SLICE_BYTES);

    const int tid  = threadIdx.x;
    const int lane = tid & 63, w = tid >> 6;       // 8 waves
    const int col  = lane & 15, quad = lane >> 4;
    const int wrow = w >> 2, wcol = w & 3;         // 2 x 4 wave grid

    const int tile  = blockIdx.x >> 3, split = blockIdx.x & 7;
    const int kbeg  = (KS * split) >> 3;
    const int kend  = (KS * (split + 1)) >> 3;
    const int kcnt  = kend - kbeg;
    const int ebase = tile * 128;

    // stage eh slice [kcnt][128] (bf16) once
    for (int idx = tid; idx < kcnt * 128; idx += 512){
        int kk = idx >> 7, e = idx & 127;
        ehs[idx] = ehT[(size_t)(kbeg + kk) * N_EDGES + ebase + e];
    }

    // load G fragments (A-operand, loop-invariant): gf[msub][ichunk]
    short8 gf[4][4];
    #pragma unroll
    for (int m = 0; m < 4; ++m){
        int e = ebase + wrow * 64 + m * 16 + col;
        int s = ei[e];
        const char* gb = (const char*)hb + ((size_t)s * H + quad * 8) * 2;
        #pragma unroll
        for (int ic = 0; ic < 4; ++ic)
            gf[m][ic] = *(const short8*)(gb + ic * 64);
    }

    float acc[4][2][4];
    #pragma unroll
    for (int m = 0; m < 4; ++m)
        #pragma unroll
        for (int ot = 0; ot < 2; ++ot)
            #pragma unroll
            for (int r = 0; r < 4; ++r) acc[m][ot][r] = 0.0f;

    const char* bsrc = (const char*)bt + (size_t)(l * KS + kbeg) * SLICE_BYTES;

    // prologue: prefetch k-slice 0 into buffer 0 (4 chunk-loads per wave)
    #pragma unroll
    for (int i = 0; i < 4; ++i){
        int c = w * 4 + i;
        async_copy16(bsrc + c * 1024 + lane * 16, smem + c * 1024 + lane * 16);
    }
    // ehs staged by all waves; also drains the prologue prefetch (one-time)
    __syncthreads();

    for (int kk = 0; kk < kcnt; ++kk){
        // (0) all waves finished reading buf[(kk+1)&1] -> safe to overwrite
        __builtin_amdgcn_s_barrier();
        if (kk + 1 < kcnt){
            const char* g = bsrc + (size_t)(kk + 1) * SLICE_BYTES;
            char* d = smem + ((kk + 1) & 1) * SLICE_BYTES;
            #pragma unroll
            for (int i = 0; i < 4; ++i){
                int c = w * 4 + i;
                async_copy16(g + c * 1024 + lane * 16, d + c * 1024 + lane * 16);
            }
            // my 4 loads for slice kk landed; slice kk+1's 4 stay in flight
            asm volatile("s_waitcnt vmcnt(4)" ::: "memory");
        } else {
            asm volatile("s_waitcnt vmcnt(0)" ::: "memory");
        }
        // (1) everyone's slice-kk loads have landed
        __builtin_amdgcn_s_barrier();

        const char* Bl = smem + (kk & 1) * SLICE_BYTES;

        // packed per-row eh scalars (C rows = quad*4+r)
        short4v ev[4];
        #pragma unroll
        for (int m = 0; m < 4; ++m)
            ev[m] = *(const short4v*)(ehs + kk * 128 + wrow * 64 + m * 16 + quad * 4);

        __builtin_amdgcn_s_setprio(1);
        #pragma unroll
        for (int ot = 0; ot < 2; ++ot){
            int t = wcol * 2 + ot;                 // o-tile index 0..7
            short8 bf[4];
            #pragma unroll
            for (int ic = 0; ic < 4; ++ic)
                bf[ic] = *(const short8*)(Bl + (t * 4 + ic) * 1024 + col * 64 + quad * 16);
            #pragma unroll
            for (int m = 0; m < 4; ++m){
                f32x4 U = {0.0f, 0.0f, 0.0f, 0.0f};
                #pragma unroll
                for (int ic = 0; ic < 4; ++ic)
                    U = __builtin_amdgcn_mfma_f32_16x16x32_bf16(gf[m][ic], bf[ic], U, 0, 0, 0);
                #pragma unroll
                for (int r = 0; r < 4; ++r)
                    acc[m][ot][r] += b2f(ev[m][r]) * U[r];
            }
        }
        __builtin_amdgcn_s_setprio(0);
    }

    // epilogue: plain stores of the split-partial
    float* pb = parts + (size_t)split * N_EDGES * H + (size_t)(ebase + wrow * 64) * H + wcol * 32;
    #pragma unroll
    for (int m = 0; m < 4; ++m)
        #pragma unroll
        for (int r = 0; r < 4; ++r){
            float* row = pb + (m * 16 + quad * 4 + r) * H;
            #pragma unroll
            for (int ot = 0; ot < 2; ++ot)
                row[ot * 16 + col] = acc[m][ot][r];
        }
}

// ---------- K4b: reduce split partials + scatter-add to agg[dst] ----------
__global__ void k_reduce_scatter(const float* __restrict__ parts, const int* __restrict__ ei,
                                 float* __restrict__ agg){
    int idx = blockIdx.x * 256 + threadIdx.x;      // E*32
    int e = idx >> 5, og = (idx & 31) << 2;
    float4 v = {0.0f, 0.0f, 0.0f, 0.0f};
    #pragma unroll
    for (int s = 0; s < SPLITS; ++s){
        float4 q = *(const float4*)(parts + (size_t)s * N_EDGES * H + (size_t)e * H + og);
        v.x += q.x; v.y += q.y; v.z += q.z; v.w += q.w;
    }
    int d = ei[N_EDGES + e];
    float* a = agg + (size_t)d * H + og;
    atomicAdd(a + 0, v.x); atomicAdd(a + 1, v.y);
    atomicAdd(a + 2, v.z); atomicAdd(a + 3, v.w);
}

// ---------- K5: node update: relu(agg/deg + h@root_w + conv_b), residual + LN ----------
__global__ void k_node(const float* __restrict__ agg, const float* __restrict__ deg,
                       const float* __restrict__ rw, const float* __restrict__ cb,
                       const float* __restrict__ lg, const float* __restrict__ lb,
                       float* __restrict__ h, short* __restrict__ hb, int l){
    __shared__ float hs[H];
    __shared__ float rsum[2], rsq[2];
    int n = blockIdx.x, o = threadIdx.x;
    float hv = h[(size_t)n * H + o];
    hs[o] = hv;
    __syncthreads();
    float root = cb[l * H + o];
    const float* W = rw + (size_t)l * H * H;
    #pragma unroll 8
    for (int i = 0; i < H; ++i) root += hs[i] * W[i * H + o];
    float a  = agg[(size_t)n * H + o] / fmaxf(deg[n], 1.0f);
    float hn = fmaxf(a + root, 0.0f);
    float v  = hv + hn;
    float s = v, q = v * v;
    #pragma unroll
    for (int off = 32; off > 0; off >>= 1){
        s += __shfl_down(s, off, 64);
        q += __shfl_down(q, off, 64);
    }
    if ((o & 63) == 0){ rsum[o >> 6] = s; rsq[o >> 6] = q; }
    __syncthreads();
    float S = rsum[0] + rsum[1], Q = rsq[0] + rsq[1];
    float mean = S * (1.0f / H);
    float var  = Q * (1.0f / H) - mean * mean;
    float out  = (v - mean) * rsqrtf(var + 1e-5f) * lg[l * H + o] + lb[l * H + o];
    h[(size_t)n * H + o]  = out;
    hb[(size_t)n * H + o] = f2b(out);
}

// ---------- K6: global mean-pool accumulation ----------
__global__ void k_pool(const float* __restrict__ h, const int* __restrict__ batch,
                       float* __restrict__ molsum, float* __restrict__ cnt){
    int idx = blockIdx.x * 256 + threadIdx.x;    // N*H
    int n = idx >> 7, o = idx & 127;
    int b = batch[n];
    atomicAdd(&molsum[b * H + o], h[idx]);
    if (o == 0) atomicAdd(&cnt[b], 1.0f);
}

// ---------- K7: head MLP ----------
__global__ void k_head(const float* __restrict__ molsum, const float* __restrict__ cnt,
                       const float* __restrict__ w1, const float* __restrict__ b1,
                       const float* __restrict__ w2, const float* __restrict__ b2,
                       float* __restrict__ out){
    __shared__ float mol[H];
    int g = blockIdx.x, t = threadIdx.x;   // 64 threads = 1 wave
    float c = fmaxf(cnt[g], 1.0f);
    mol[t]      = molsum[g * H + t] / c;
    mol[t + 64] = molsum[g * H + t + 64] / c;
    __syncthreads();
    float a = b1[t];
    #pragma unroll 8
    for (int i = 0; i < H; ++i) a += mol[i] * w1[i * 64 + t];
    float hid = gelu_exact(a);
    float p = hid * w2[t];
    #pragma unroll
    for (int off = 32; off > 0; off >>= 1) p += __shfl_down(p, off, 64);
    if (t == 0) out[g] = p + b2[0];
}

extern "C" void kernel_launch(void* const* d_in, const int* in_sizes, int n_in,
                              void* d_out, int out_size, void* d_ws, size_t ws_size,
                              hipStream_t stream){
    (void)in_sizes; (void)n_in; (void)out_size; (void)ws_size;
    const float* x     = (const float*)d_in[0];
    const int*   ei    = (const int*)  d_in[1];
    const float* ea    = (const float*)d_in[2];
    const int*   batch = (const int*)  d_in[3];
    const float* aw    = (const float*)d_in[4];
    const float* ab    = (const float*)d_in[5];
    const float* e1w   = (const float*)d_in[6];
    const float* e1b   = (const float*)d_in[7];
    const float* e2w   = (const float*)d_in[8];
    const float* e2b   = (const float*)d_in[9];
    const float* rw    = (const float*)d_in[10];
    const float* cb    = (const float*)d_in[11];
    const float* lg    = (const float*)d_in[12];
    const float* lb    = (const float*)d_in[13];
    const float* hw1   = (const float*)d_in[14];
    const float* hb1   = (const float*)d_in[15];
    const float* hw2   = (const float*)d_in[16];
    const float* hb2   = (const float*)d_in[17];
    float* out = (float*)d_out;

    char* p = (char*)d_ws;
    auto carve = [&](size_t bytes){ char* r = p; p += (bytes + 255) & ~(size_t)255; return r; };
    short* bt     = (short*)carve((size_t)NL * KS * SLICE_SH * 2);  // 12.7 MB
    float* h      = (float*)carve((size_t)N_NODES * H * 4);         // 2 MB
    short* hbuf   = (short*)carve((size_t)N_NODES * H * 2);         // 1 MB
    short* ehT    = (short*)carve((size_t)KS * N_EDGES * 2);        // 2.1 MB
    float* parts  = (float*)carve((size_t)SPLITS * N_EDGES * H * 4);// 33.5 MB
    float* agg    = (float*)carve((size_t)N_NODES * H * 4);         // 2 MB
    float* deg    = (float*)carve((size_t)N_NODES * 4);
    float* molsum = (float*)carve((size_t)NGRAPH * H * 4);
    float* cnt    = (float*)carve((size_t)NGRAPH * 4);

    hipMemsetAsync(deg, 0, (size_t)N_NODES * 4, stream);
    hipMemsetAsync(molsum, 0, (size_t)NGRAPH * H * 4, stream);
    hipMemsetAsync(cnt, 0, (size_t)NGRAPH * 4, stream);

    k_prep_b<<<NL * KS * 4, 256, 0, stream>>>(e2w, e2b, bt);
    k_atom<<<N_NODES, H, 0, stream>>>(x, aw, ab, h, hbuf);
    k_deg<<<N_EDGES / 256, 256, 0, stream>>>(ei, deg);

    for (int l = 0; l < NL; ++l){
        k_edge_mlp<<<N_EDGES, H, 0, stream>>>(ea, e1w, e1b, ehT, l);
        hipMemsetAsync(agg, 0, (size_t)N_NODES * H * 4, stream);
        k_msg_gemm<<<64 * SPLITS, 512, 0, stream>>>(bt, ehT, hbuf, ei, parts, l);
        k_reduce_scatter<<<N_EDGES * 32 / 256, 256, 0, stream>>>(parts, ei, agg);
        k_node<<<N_NODES, H, 0, stream>>>(agg, deg, rw, cb, lg, lb, h, hbuf, l);
    }
    k_pool<<<N_NODES * H / 256, 256, 0, stream>>>(h, batch, molsum, cnt);
    k_head<<<NGRAPH, 64, 0, stream>>>(molsum, cnt, hw1, hb1, hw2, hb2, out);
}

// Round 4
// 551.128 us; speedup vs baseline: 1.0855x; 1.0855x over previous
//
#include <hip/hip_runtime.h>
#include <hip/hip_bf16.h>

#define N_NODES 4096
#define N_EDGES 8192
#define NGRAPH  256
#define AFEAT   9
#define BFEAT   4
#define H       128
#define NL      3
#define KS      129              // k-slices including the e2_b bias slice
#define SPLITS  8
#define SLICE_SH    16384        // shorts per k-slice (chunked layout)
#define SLICE_BYTES 32768        // bytes per k-slice
#define HALF_BYTES  16384        // per-block o-half of one slice

typedef short short8 __attribute__((ext_vector_type(8)));
typedef short short4v __attribute__((ext_vector_type(4)));
typedef float f32x4 __attribute__((ext_vector_type(4)));

// ---- bf16 helpers (RNE, finite inputs) ----
__device__ __forceinline__ short f2b(float f){
    union { float f; unsigned u; } c; c.f = f;
    unsigned r = c.u + 0x7FFFu + ((c.u >> 16) & 1u);
    return (short)(r >> 16);
}
__device__ __forceinline__ float b2f(short b){
    union { unsigned u; float f; } c;
    c.u = ((unsigned)(unsigned short)b) << 16;
    return c.f;
}
__device__ __forceinline__ float gelu_exact(float x){
    return 0.5f * x * (1.0f + erff(x * 0.70710678118654752440f));
}
__device__ __forceinline__ void async_copy16(const void* g, void* l){
    typedef __attribute__((address_space(1))) const char AS1C;
    typedef __attribute__((address_space(3))) char AS3;
    __builtin_amdgcn_global_load_lds((AS1C*)g, (AS3*)l, 16, 0, 0);
}

// ---------- K0: e2_w/e2_b -> bt[l][k] in fragment-chunk order ----------
// Element B_k[i][o] stored at short offset
// ((((o>>4)*4 + (i>>5))*16 + (o&15))*4 + ((i>>3)&3))*8 + (i&7).
// For fixed (o-tile t, ic): a wave's 64 lanes (col=o&15, quad) read one
// contiguous aligned 1 KB line (byte off (t*4+ic)*1024 + col*64 + quad*16).
__global__ void k_prep_b(const float* __restrict__ e2w, const float* __restrict__ e2b,
                         short* __restrict__ bt){
    __shared__ float ts[H][33];
    int b  = blockIdx.x;
    int o0 = (b & 3) * 32;
    int k  = (b >> 2) % KS;
    int l  = (b >> 2) / KS;
    const float* src = (k < H) ? (e2w + ((size_t)l * H + k) * (H * H))
                               : (e2b + (size_t)l * (H * H));
    for (int idx = threadIdx.x; idx < H * 32; idx += 256){
        int i = idx >> 5, op = idx & 31;
        ts[i][op] = src[i * H + o0 + op];
    }
    __syncthreads();
    short* dst = bt + (size_t)(l * KS + k) * SLICE_SH;
    for (int idx = threadIdx.x; idx < 32 * H; idx += 256){
        int j    = idx & 7;
        int quad = (idx >> 3) & 3;
        int op   = (idx >> 5) & 31;
        int ic   = idx >> 10;
        int i    = ic * 32 + quad * 8 + j;
        int o    = o0 + op;
        dst[((((o >> 4) * 4 + ic) * 16 + (o & 15)) * 4 + quad) * 8 + j] = f2b(ts[i][op]);
    }
}

// ---------- K1: h0 = relu(x @ atom_w + atom_b) ----------
__global__ void k_atom(const float* __restrict__ x, const float* __restrict__ aw,
                       const float* __restrict__ ab, float* __restrict__ h,
                       short* __restrict__ hb){
    __shared__ float xs[AFEAT];
    int n = blockIdx.x, o = threadIdx.x;
    if (o < AFEAT) xs[o] = x[n * AFEAT + o];
    __syncthreads();
    float a = ab[o];
    #pragma unroll
    for (int f = 0; f < AFEAT; ++f) a += xs[f] * aw[f * H + o];
    a = fmaxf(a, 0.0f);
    h[(size_t)n * H + o]  = a;
    hb[(size_t)n * H + o] = f2b(a);
}

// ---------- K2: in-degree (int histogram) ----------
__global__ void k_deg(const int* __restrict__ ei, int* __restrict__ ideg){
    int e = blockIdx.x * 256 + threadIdx.x;
    if (e < N_EDGES) atomicAdd(&ideg[ei[N_EDGES + e]], 1);
}

// ---------- K2b: exclusive scan -> row_ptr + cursor (one block, once) ----------
__global__ void k_scan(const int* __restrict__ ideg, int* __restrict__ row_ptr,
                       int* __restrict__ cursor){
    __shared__ int part[256];
    int t = threadIdx.x;
    int base = t * 16;
    int loc[16]; int s = 0;
    #pragma unroll
    for (int i = 0; i < 16; ++i){ loc[i] = s; s += ideg[base + i]; }
    part[t] = s;
    __syncthreads();
    if (t == 0){
        int run = 0;
        for (int i = 0; i < 256; ++i){ int v = part[i]; part[i] = run; run += v; }
        row_ptr[N_NODES] = run;
    }
    __syncthreads();
    int off = part[t];
    #pragma unroll
    for (int i = 0; i < 16; ++i){
        row_ptr[base + i] = off + loc[i];
        cursor[base + i]  = off + loc[i];
    }
}

// ---------- K2c: fill CSR edge-id list (once) ----------
__global__ void k_fill(const int* __restrict__ ei, int* __restrict__ cursor,
                       int* __restrict__ eidx){
    int e = blockIdx.x * 256 + threadIdx.x;
    if (e < N_EDGES){
        int d = ei[N_EDGES + e];
        int pos = atomicAdd(&cursor[d], 1);
        eidx[pos] = e;
    }
}

// ---------- K3: eh = gelu(edge_attr @ e1_w + e1_b) for ALL layers, [l][k][e] bf16 ----------
__global__ void k_edge_mlp(const float* __restrict__ ea, const float* __restrict__ w1,
                           const float* __restrict__ b1, short* __restrict__ ehT){
    __shared__ float as[BFEAT];
    int e = blockIdx.x, o = threadIdx.x;
    if (o < BFEAT) as[o] = ea[e * BFEAT + o];
    __syncthreads();
    #pragma unroll
    for (int l = 0; l < NL; ++l){
        float v = b1[l * H + o];
        #pragma unroll
        for (int f = 0; f < BFEAT; ++f) v += as[f] * w1[(l * BFEAT + f) * H + o];
        v = gelu_exact(v);
        ehT[((size_t)l * KS + o) * N_EDGES + e] = f2b(v);
        if (o == 0) ehT[((size_t)l * KS + H) * N_EDGES + e] = f2b(1.0f);   // bias slice
    }
}

// ---------- K4: the big fused GEMM: parts[split][e][o] = sum_k eh[e,k]*(g[e] @ B_k) ----------
// Block = 128 edges x 64 out-cols (o-half) x 1/8 of K. LDS double-buffered
// 16 KB half-slices, counted-vmcnt prefetch. LDS 37.1 KB -> 4 blocks/CU
// -> 4 waves/SIMD. split = bid&7 pins each split's B stream to one XCD L2.
__global__ __launch_bounds__(256, 4)
void k_msg_gemm(const short* __restrict__ bt, const short* __restrict__ ehT,
                const short* __restrict__ hb, const int* __restrict__ ei,
                float* __restrict__ parts, int l){
    __shared__ __align__(16) char smem[2 * HALF_BYTES + 17 * H * 2];
    short* ehs = (short*)(smem + 2 * HALF_BYTES);

    const int tid  = threadIdx.x;
    const int lane = tid & 63, w = tid >> 6;       // 4 waves
    const int col  = lane & 15, quad = lane >> 4;
    const int wrow = w >> 1, wcol = w & 1;         // 2 x 2 wave grid

    const int split = blockIdx.x & 7;
    const int oh    = (blockIdx.x >> 3) & 1;
    const int tile  = blockIdx.x >> 4;
    const int kbeg  = (KS * split) >> 3;
    const int kend  = (KS * (split + 1)) >> 3;
    const int kcnt  = kend - kbeg;
    const int ebase = tile * 128;

    // stage eh slice [kcnt][128] (bf16) once
    for (int idx = tid; idx < kcnt * 128; idx += 256){
        int kk = idx >> 7, e = idx & 127;
        ehs[idx] = ehT[((size_t)(l * KS + kbeg + kk)) * N_EDGES + ebase + e];
    }

    // load G fragments (A-operand, loop-invariant): gf[msub][ichunk]
    short8 gf[4][4];
    #pragma unroll
    for (int m = 0; m < 4; ++m){
        int e = ebase + wrow * 64 + m * 16 + col;
        int s = ei[e];
        const char* gb = (const char*)hb + ((size_t)s * H + quad * 8) * 2;
        #pragma unroll
        for (int ic = 0; ic < 4; ++ic)
            gf[m][ic] = *(const short8*)(gb + ic * 64);
    }

    float acc[4][2][4];
    #pragma unroll
    for (int m = 0; m < 4; ++m)
        #pragma unroll
        for (int ot = 0; ot < 2; ++ot)
            #pragma unroll
            for (int r = 0; r < 4; ++r) acc[m][ot][r] = 0.0f;

    // this block's o-half of the B stream
    const char* bsrc = (const char*)bt + (size_t)(l * KS + kbeg) * SLICE_BYTES
                     + oh * HALF_BYTES;

    // prologue: prefetch half-slice 0 into buffer 0 (4 chunk-loads per wave)
    #pragma unroll
    for (int i = 0; i < 4; ++i){
        int c = w * 4 + i;
        async_copy16(bsrc + c * 1024 + lane * 16, smem + c * 1024 + lane * 16);
    }
    // ehs staged by all waves; also drains the prologue prefetch (one-time)
    __syncthreads();

    for (int kk = 0; kk < kcnt; ++kk){
        // (0) all waves finished reading buf[(kk+1)&1] -> safe to overwrite
        __builtin_amdgcn_s_barrier();
        if (kk + 1 < kcnt){
            const char* g = bsrc + (size_t)(kk + 1) * SLICE_BYTES;
            char* d = smem + ((kk + 1) & 1) * HALF_BYTES;
            #pragma unroll
            for (int i = 0; i < 4; ++i){
                int c = w * 4 + i;
                async_copy16(g + c * 1024 + lane * 16, d + c * 1024 + lane * 16);
            }
            // my 4 loads for slice kk landed; slice kk+1's 4 stay in flight
            asm volatile("s_waitcnt vmcnt(4)" ::: "memory");
        } else {
            asm volatile("s_waitcnt vmcnt(0)" ::: "memory");
        }
        // (1) everyone's slice-kk loads have landed
        __builtin_amdgcn_s_barrier();

        const char* Bl = smem + (kk & 1) * HALF_BYTES;

        // packed per-row eh scalars (C rows = quad*4+r)
        short4v ev[4];
        #pragma unroll
        for (int m = 0; m < 4; ++m)
            ev[m] = *(const short4v*)(ehs + kk * 128 + wrow * 64 + m * 16 + quad * 4);

        __builtin_amdgcn_s_setprio(1);
        #pragma unroll
        for (int ot = 0; ot < 2; ++ot){
            int tl = wcol * 2 + ot;                // local o-tile 0..3
            short8 bf[4];
            #pragma unroll
            for (int ic = 0; ic < 4; ++ic)
                bf[ic] = *(const short8*)(Bl + (tl * 4 + ic) * 1024 + col * 64 + quad * 16);
            #pragma unroll
            for (int m = 0; m < 4; ++m){
                f32x4 U = {0.0f, 0.0f, 0.0f, 0.0f};
                #pragma unroll
                for (int ic = 0; ic < 4; ++ic)
                    U = __builtin_amdgcn_mfma_f32_16x16x32_bf16(gf[m][ic], bf[ic], U, 0, 0, 0);
                #pragma unroll
                for (int r = 0; r < 4; ++r)
                    acc[m][ot][r] += b2f(ev[m][r]) * U[r];
            }
        }
        __builtin_amdgcn_s_setprio(0);
    }

    // epilogue: plain stores of the split-partial
    float* pb = parts + (size_t)split * N_EDGES * H + (size_t)(ebase + wrow * 64) * H
              + oh * 64 + wcol * 32;
    #pragma unroll
    for (int m = 0; m < 4; ++m)
        #pragma unroll
        for (int r = 0; r < 4; ++r){
            float* row = pb + (m * 16 + quad * 4 + r) * H;
            #pragma unroll
            for (int ot = 0; ot < 2; ++ot)
                row[ot * 16 + col] = acc[m][ot][r];
        }
}

// ---------- K5: node update with fused CSR gather over split partials ----------
__global__ void k_node(const float* __restrict__ parts, const int* __restrict__ eidx,
                       const int* __restrict__ row_ptr,
                       const float* __restrict__ rw, const float* __restrict__ cb,
                       const float* __restrict__ lg, const float* __restrict__ lb,
                       float* __restrict__ h, short* __restrict__ hb, int l){
    __shared__ float hs[H];
    __shared__ float rsum[2], rsq[2];
    int n = blockIdx.x, o = threadIdx.x;
    float hv = h[(size_t)n * H + o];
    hs[o] = hv;
    int p0 = row_ptr[n], p1 = row_ptr[n + 1];
    float a = 0.0f;
    for (int p = p0; p < p1; ++p){
        const float* pr = parts + (size_t)eidx[p] * H + o;
        #pragma unroll
        for (int s = 0; s < SPLITS; ++s) a += pr[(size_t)s * N_EDGES * H];
    }
    int d = p1 - p0;
    a *= 1.0f / (float)(d > 0 ? d : 1);
    __syncthreads();
    float root = cb[l * H + o];
    const float* W = rw + (size_t)l * H * H;
    #pragma unroll 8
    for (int i = 0; i < H; ++i) root += hs[i] * W[i * H + o];
    float hn = fmaxf(a + root, 0.0f);
    float v  = hv + hn;
    float s = v, q = v * v;
    #pragma unroll
    for (int off = 32; off > 0; off >>= 1){
        s += __shfl_down(s, off, 64);
        q += __shfl_down(q, off, 64);
    }
    if ((o & 63) == 0){ rsum[o >> 6] = s; rsq[o >> 6] = q; }
    __syncthreads();
    float S = rsum[0] + rsum[1], Q = rsq[0] + rsq[1];
    float mean = S * (1.0f / H);
    float var  = Q * (1.0f / H) - mean * mean;
    float out  = (v - mean) * rsqrtf(var + 1e-5f) * lg[l * H + o] + lb[l * H + o];
    h[(size_t)n * H + o]  = out;
    hb[(size_t)n * H + o] = f2b(out);
}

// ---------- K6: global mean-pool accumulation ----------
__global__ void k_pool(const float* __restrict__ h, const int* __restrict__ batch,
                       float* __restrict__ molsum, float* __restrict__ cnt){
    int idx = blockIdx.x * 256 + threadIdx.x;    // N*H
    int n = idx >> 7, o = idx & 127;
    int b = batch[n];
    atomicAdd(&molsum[b * H + o], h[idx]);
    if (o == 0) atomicAdd(&cnt[b], 1.0f);
}

// ---------- K7: head MLP ----------
__global__ void k_head(const float* __restrict__ molsum, const float* __restrict__ cnt,
                       const float* __restrict__ w1, const float* __restrict__ b1,
                       const float* __restrict__ w2, const float* __restrict__ b2,
                       float* __restrict__ out){
    __shared__ float mol[H];
    int g = blockIdx.x, t = threadIdx.x;   // 64 threads = 1 wave
    float c = fmaxf(cnt[g], 1.0f);
    mol[t]      = molsum[g * H + t] / c;
    mol[t + 64] = molsum[g * H + t + 64] / c;
    __syncthreads();
    float a = b1[t];
    #pragma unroll 8
    for (int i = 0; i < H; ++i) a += mol[i] * w1[i * 64 + t];
    float hid = gelu_exact(a);
    float p = hid * w2[t];
    #pragma unroll
    for (int off = 32; off > 0; off >>= 1) p += __shfl_down(p, off, 64);
    if (t == 0) out[g] = p + b2[0];
}

extern "C" void kernel_launch(void* const* d_in, const int* in_sizes, int n_in,
                              void* d_out, int out_size, void* d_ws, size_t ws_size,
                              hipStream_t stream){
    (void)in_sizes; (void)n_in; (void)out_size; (void)ws_size;
    const float* x     = (const float*)d_in[0];
    const int*   ei    = (const int*)  d_in[1];
    const float* ea    = (const float*)d_in[2];
    const int*   batch = (const int*)  d_in[3];
    const float* aw    = (const float*)d_in[4];
    const float* ab    = (const float*)d_in[5];
    const float* e1w   = (const float*)d_in[6];
    const float* e1b   = (const float*)d_in[7];
    const float* e2w   = (const float*)d_in[8];
    const float* e2b   = (const float*)d_in[9];
    const float* rw    = (const float*)d_in[10];
    const float* cb    = (const float*)d_in[11];
    const float* lg    = (const float*)d_in[12];
    const float* lb    = (const float*)d_in[13];
    const float* hw1   = (const float*)d_in[14];
    const float* hb1   = (const float*)d_in[15];
    const float* hw2   = (const float*)d_in[16];
    const float* hb2   = (const float*)d_in[17];
    float* out = (float*)d_out;

    char* p = (char*)d_ws;
    auto carve = [&](size_t bytes){ char* r = p; p += (bytes + 255) & ~(size_t)255; return r; };
    short* bt     = (short*)carve((size_t)NL * KS * SLICE_SH * 2);    // 12.7 MB
    float* h      = (float*)carve((size_t)N_NODES * H * 4);           // 2 MB
    short* hbuf   = (short*)carve((size_t)N_NODES * H * 2);           // 1 MB
    short* ehT    = (short*)carve((size_t)NL * KS * N_EDGES * 2);     // 6.3 MB
    float* parts  = (float*)carve((size_t)SPLITS * N_EDGES * H * 4);  // 33.5 MB
    int*   ideg   = (int*)  carve((size_t)N_NODES * 4);
    int*   row_ptr= (int*)  carve((size_t)(N_NODES + 1) * 4);
    int*   cursor = (int*)  carve((size_t)N_NODES * 4);
    int*   eidx   = (int*)  carve((size_t)N_EDGES * 4);
    float* molsum = (float*)carve((size_t)NGRAPH * H * 4);
    float* cnt    = (float*)carve((size_t)NGRAPH * 4);

    hipMemsetAsync(ideg, 0, (size_t)N_NODES * 4, stream);
    hipMemsetAsync(molsum, 0, (size_t)NGRAPH * H * 4, stream);
    hipMemsetAsync(cnt, 0, (size_t)NGRAPH * 4, stream);

    k_prep_b<<<NL * KS * 4, 256, 0, stream>>>(e2w, e2b, bt);
    k_atom<<<N_NODES, H, 0, stream>>>(x, aw, ab, h, hbuf);
    k_deg<<<N_EDGES / 256, 256, 0, stream>>>(ei, ideg);
    k_scan<<<1, 256, 0, stream>>>(ideg, row_ptr, cursor);
    k_fill<<<N_EDGES / 256, 256, 0, stream>>>(ei, cursor, eidx);
    k_edge_mlp<<<N_EDGES, H, 0, stream>>>(ea, e1w, e1b, ehT);

    for (int l = 0; l < NL; ++l){
        k_msg_gemm<<<64 * 2 * SPLITS, 256, 0, stream>>>(bt, ehT, hbuf, ei, parts, l);
        k_node<<<N_NODES, H, 0, stream>>>(parts, eidx, row_ptr, rw, cb, lg, lb, h, hbuf, l);
    }
    k_pool<<<N_NODES * H / 256, 256, 0, stream>>>(h, batch, molsum, cnt);
    k_head<<<NGRAPH, 64, 0, stream>>>(molsum, cnt, hw1, hb1, hw2, hb2, out);
}

// Round 5
// 331.393 us; speedup vs baseline: 1.8052x; 1.6631x over previous
//
#include <hip/hip_runtime.h>
#include <hip/hip_bf16.h>

#define N_NODES 4096
#define N_EDGES 8192
#define NGRAPH  256
#define AFEAT   9
#define BFEAT   4
#define H       128
#define NL      3
#define KS      129              // k-slices including the e2_b bias slice
#define SPLITS  8
#define SLICE_SH    16384        // shorts per k-slice (chunked layout)
#define SLICE_BYTES 32768        // bytes per k-slice
#define HALF_BYTES  16384        // per-block o-half of one slice

typedef short short8 __attribute__((ext_vector_type(8)));
typedef short short4v __attribute__((ext_vector_type(4)));
typedef float f32x4 __attribute__((ext_vector_type(4)));

// ---- bf16 helpers (RNE, finite inputs) ----
__device__ __forceinline__ short f2b(float f){
    union { float f; unsigned u; } c; c.f = f;
    unsigned r = c.u + 0x7FFFu + ((c.u >> 16) & 1u);
    return (short)(r >> 16);
}
__device__ __forceinline__ float b2f(short b){
    union { unsigned u; float f; } c;
    c.u = ((unsigned)(unsigned short)b) << 16;
    return c.f;
}
__device__ __forceinline__ float gelu_exact(float x){
    return 0.5f * x * (1.0f + erff(x * 0.70710678118654752440f));
}
__device__ __forceinline__ void async_copy16(const void* g, void* l){
    typedef __attribute__((address_space(1))) const char AS1C;
    typedef __attribute__((address_space(3))) char AS3;
    __builtin_amdgcn_global_load_lds((AS1C*)g, (AS3*)l, 16, 0, 0);
}

// ---------- K0: e2_w/e2_b -> bt[l][k] in fragment-chunk order ----------
// Element B_k[i][o] stored at short offset
// (((o>>4)*4 + (i>>5))*64 + ((i>>3)&3)*16 + (o&15))*8 + (i&7).
// For fixed (o-tile t, ic): the 8 shorts a lane (col=o&15, quad=(i>>3)&3)
// needs sit at byte off (t*4+ic)*1024 + lane*16 -- the wave's fragment
// read is one perfectly-sequential aligned 1 KB line (bank-conflict-free,
// same for the global_load_lds staging copy).
__global__ void k_prep_b(const float* __restrict__ e2w, const float* __restrict__ e2b,
                         short* __restrict__ bt){
    __shared__ float ts[H][33];
    int b  = blockIdx.x;
    int o0 = (b & 3) * 32;
    int k  = (b >> 2) % KS;
    int l  = (b >> 2) / KS;
    const float* src = (k < H) ? (e2w + ((size_t)l * H + k) * (H * H))
                               : (e2b + (size_t)l * (H * H));
    for (int idx = threadIdx.x; idx < H * 32; idx += 256){
        int i = idx >> 5, op = idx & 31;
        ts[i][op] = src[i * H + o0 + op];
    }
    __syncthreads();
    short* dst = bt + (size_t)(l * KS + k) * SLICE_SH;
    for (int idx = threadIdx.x; idx < 32 * H; idx += 256){
        int j    = idx & 7;
        int quad = (idx >> 3) & 3;
        int op   = (idx >> 5) & 31;
        int ic   = idx >> 10;
        int i    = ic * 32 + quad * 8 + j;
        int o    = o0 + op;
        dst[((((o >> 4) * 4 + ic) * 64) + quad * 16 + (o & 15)) * 8 + j] = f2b(ts[i][op]);
    }
}

// ---------- K1: h0 = relu(x @ atom_w + atom_b) ----------
__global__ void k_atom(const float* __restrict__ x, const float* __restrict__ aw,
                       const float* __restrict__ ab, float* __restrict__ h,
                       short* __restrict__ hb){
    __shared__ float xs[AFEAT];
    int n = blockIdx.x, o = threadIdx.x;
    if (o < AFEAT) xs[o] = x[n * AFEAT + o];
    __syncthreads();
    float a = ab[o];
    #pragma unroll
    for (int f = 0; f < AFEAT; ++f) a += xs[f] * aw[f * H + o];
    a = fmaxf(a, 0.0f);
    h[(size_t)n * H + o]  = a;
    hb[(size_t)n * H + o] = f2b(a);
}

// ---------- K2: in-degree (int histogram) ----------
__global__ void k_deg(const int* __restrict__ ei, int* __restrict__ ideg){
    int e = blockIdx.x * 256 + threadIdx.x;
    if (e < N_EDGES) atomicAdd(&ideg[ei[N_EDGES + e]], 1);
}

// ---------- K2b: exclusive scan -> row_ptr + cursor (one block, once) ----------
__global__ void k_scan(const int* __restrict__ ideg, int* __restrict__ row_ptr,
                       int* __restrict__ cursor){
    __shared__ int part[256];
    int t = threadIdx.x;
    int base = t * 16;
    int loc[16]; int s = 0;
    #pragma unroll
    for (int i = 0; i < 16; ++i){ loc[i] = s; s += ideg[base + i]; }
    part[t] = s;
    __syncthreads();
    if (t == 0){
        int run = 0;
        for (int i = 0; i < 256; ++i){ int v = part[i]; part[i] = run; run += v; }
        row_ptr[N_NODES] = run;
    }
    __syncthreads();
    int off = part[t];
    #pragma unroll
    for (int i = 0; i < 16; ++i){
        row_ptr[base + i] = off + loc[i];
        cursor[base + i]  = off + loc[i];
    }
}

// ---------- K2c: fill CSR edge-id list (once) ----------
__global__ void k_fill(const int* __restrict__ ei, int* __restrict__ cursor,
                       int* __restrict__ eidx){
    int e = blockIdx.x * 256 + threadIdx.x;
    if (e < N_EDGES){
        int d = ei[N_EDGES + e];
        int pos = atomicAdd(&cursor[d], 1);
        eidx[pos] = e;
    }
}

// ---------- K3: eh = gelu(edge_attr @ e1_w + e1_b) for ALL layers, [l][k][e] bf16 ----------
__global__ void k_edge_mlp(const float* __restrict__ ea, const float* __restrict__ w1,
                           const float* __restrict__ b1, short* __restrict__ ehT){
    __shared__ float as[BFEAT];
    int e = blockIdx.x, o = threadIdx.x;
    if (o < BFEAT) as[o] = ea[e * BFEAT + o];
    __syncthreads();
    #pragma unroll
    for (int l = 0; l < NL; ++l){
        float v = b1[l * H + o];
        #pragma unroll
        for (int f = 0; f < BFEAT; ++f) v += as[f] * w1[(l * BFEAT + f) * H + o];
        v = gelu_exact(v);
        ehT[((size_t)l * KS + o) * N_EDGES + e] = f2b(v);
        if (o == 0) ehT[((size_t)l * KS + H) * N_EDGES + e] = f2b(1.0f);   // bias slice
    }
}

// ---------- K4: the big fused GEMM: parts[split][e][o] = sum_k eh[e,k]*(g[e] @ B_k) ----------
// Block = 128 edges x 64 out-cols (o-half) x 1/8 of K. LDS double-buffered
// 16 KB half-slices, counted-vmcnt prefetch. LDS 37.1 KB -> 4 blocks/CU
// -> 4 waves/SIMD. split = bid&7 pins each split's B stream to one XCD L2.
// launch_bounds min=2: empirically arg2=4 caps VGPR at 64 (spill storm,
// rounds 3-4); arg2=2 allows >=124 regs -- kernel needs ~105, no spill.
__global__ __launch_bounds__(256, 2)
void k_msg_gemm(const short* __restrict__ bt, const short* __restrict__ ehT,
                const short* __restrict__ hb, const int* __restrict__ ei,
                float* __restrict__ parts, int l){
    __shared__ __align__(16) char smem[2 * HALF_BYTES + 17 * H * 2];
    short* ehs = (short*)(smem + 2 * HALF_BYTES);

    const int tid  = threadIdx.x;
    const int lane = tid & 63, w = tid >> 6;       // 4 waves
    const int col  = lane & 15, quad = lane >> 4;
    const int wrow = w >> 1, wcol = w & 1;         // 2 x 2 wave grid

    const int split = blockIdx.x & 7;
    const int oh    = (blockIdx.x >> 3) & 1;
    const int tile  = blockIdx.x >> 4;
    const int kbeg  = (KS * split) >> 3;
    const int kend  = (KS * (split + 1)) >> 3;
    const int kcnt  = kend - kbeg;
    const int ebase = tile * 128;

    // stage eh slice [kcnt][128] (bf16) once
    for (int idx = tid; idx < kcnt * 128; idx += 256){
        int kk = idx >> 7, e = idx & 127;
        ehs[idx] = ehT[((size_t)(l * KS + kbeg + kk)) * N_EDGES + ebase + e];
    }

    // load G fragments (A-operand, loop-invariant): gf[msub][ichunk]
    short8 gf[4][4];
    #pragma unroll
    for (int m = 0; m < 4; ++m){
        int e = ebase + wrow * 64 + m * 16 + col;
        int s = ei[e];
        const char* gb = (const char*)hb + ((size_t)s * H + quad * 8) * 2;
        #pragma unroll
        for (int ic = 0; ic < 4; ++ic)
            gf[m][ic] = *(const short8*)(gb + ic * 64);
    }

    float acc[4][2][4];
    #pragma unroll
    for (int m = 0; m < 4; ++m)
        #pragma unroll
        for (int ot = 0; ot < 2; ++ot)
            #pragma unroll
            for (int r = 0; r < 4; ++r) acc[m][ot][r] = 0.0f;

    // this block's o-half of the B stream
    const char* bsrc = (const char*)bt + (size_t)(l * KS + kbeg) * SLICE_BYTES
                     + oh * HALF_BYTES;

    // prologue: prefetch half-slice 0 into buffer 0 (4 chunk-loads per wave)
    #pragma unroll
    for (int i = 0; i < 4; ++i){
        int c = w * 4 + i;
        async_copy16(bsrc + c * 1024 + lane * 16, smem + c * 1024 + lane * 16);
    }
    // ehs staged by all waves; also drains the prologue prefetch (one-time)
    __syncthreads();

    for (int kk = 0; kk < kcnt; ++kk){
        // (0) all waves finished reading buf[(kk+1)&1] -> safe to overwrite
        __builtin_amdgcn_s_barrier();
        if (kk + 1 < kcnt){
            const char* g = bsrc + (size_t)(kk + 1) * SLICE_BYTES;
            char* d = smem + ((kk + 1) & 1) * HALF_BYTES;
            #pragma unroll
            for (int i = 0; i < 4; ++i){
                int c = w * 4 + i;
                async_copy16(g + c * 1024 + lane * 16, d + c * 1024 + lane * 16);
            }
            // my 4 loads for slice kk landed; slice kk+1's 4 stay in flight
            asm volatile("s_waitcnt vmcnt(4)" ::: "memory");
        } else {
            asm volatile("s_waitcnt vmcnt(0)" ::: "memory");
        }
        // (1) everyone's slice-kk loads have landed
        __builtin_amdgcn_s_barrier();

        const char* Bl = smem + (kk & 1) * HALF_BYTES;

        // packed per-row eh scalars (C rows = quad*4+r)
        short4v ev[4];
        #pragma unroll
        for (int m = 0; m < 4; ++m)
            ev[m] = *(const short4v*)(ehs + kk * 128 + wrow * 64 + m * 16 + quad * 4);

        __builtin_amdgcn_s_setprio(1);
        #pragma unroll
        for (int ot = 0; ot < 2; ++ot){
            int tl = wcol * 2 + ot;                // local o-tile 0..3
            short8 bf[4];
            #pragma unroll
            for (int ic = 0; ic < 4; ++ic)
                bf[ic] = *(const short8*)(Bl + (tl * 4 + ic) * 1024 + lane * 16);
            #pragma unroll
            for (int m = 0; m < 4; ++m){
                f32x4 U = {0.0f, 0.0f, 0.0f, 0.0f};
                #pragma unroll
                for (int ic = 0; ic < 4; ++ic)
                    U = __builtin_amdgcn_mfma_f32_16x16x32_bf16(gf[m][ic], bf[ic], U, 0, 0, 0);
                #pragma unroll
                for (int r = 0; r < 4; ++r)
                    acc[m][ot][r] += b2f(ev[m][r]) * U[r];
            }
        }
        __builtin_amdgcn_s_setprio(0);
    }

    // epilogue: plain stores of the split-partial
    float* pb = parts + (size_t)split * N_EDGES * H + (size_t)(ebase + wrow * 64) * H
              + oh * 64 + wcol * 32;
    #pragma unroll
    for (int m = 0; m < 4; ++m)
        #pragma unroll
        for (int r = 0; r < 4; ++r){
            float* row = pb + (m * 16 + quad * 4 + r) * H;
            #pragma unroll
            for (int ot = 0; ot < 2; ++ot)
                row[ot * 16 + col] = acc[m][ot][r];
        }
}

// ---------- K5: node update with fused CSR gather over split partials ----------
__global__ void k_node(const float* __restrict__ parts, const int* __restrict__ eidx,
                       const int* __restrict__ row_ptr,
                       const float* __restrict__ rw, const float* __restrict__ cb,
                       const float* __restrict__ lg, const float* __restrict__ lb,
                       float* __restrict__ h, short* __restrict__ hb, int l){
    __shared__ float hs[H];
    __shared__ float rsum[2], rsq[2];
    int n = blockIdx.x, o = threadIdx.x;
    float hv = h[(size_t)n * H + o];
    hs[o] = hv;
    int p0 = row_ptr[n], p1 = row_ptr[n + 1];
    float a = 0.0f;
    for (int p = p0; p < p1; ++p){
        const float* pr = parts + (size_t)eidx[p] * H + o;
        #pragma unroll
        for (int s = 0; s < SPLITS; ++s) a += pr[(size_t)s * N_EDGES * H];
    }
    int d = p1 - p0;
    a *= 1.0f / (float)(d > 0 ? d : 1);
    __syncthreads();
    float root = cb[l * H + o];
    const float* W = rw + (size_t)l * H * H;
    #pragma unroll 8
    for (int i = 0; i < H; ++i) root += hs[i] * W[i * H + o];
    float hn = fmaxf(a + root, 0.0f);
    float v  = hv + hn;
    float s = v, q = v * v;
    #pragma unroll
    for (int off = 32; off > 0; off >>= 1){
        s += __shfl_down(s, off, 64);
        q += __shfl_down(q, off, 64);
    }
    if ((o & 63) == 0){ rsum[o >> 6] = s; rsq[o >> 6] = q; }
    __syncthreads();
    float S = rsum[0] + rsum[1], Q = rsq[0] + rsq[1];
    float mean = S * (1.0f / H);
    float var  = Q * (1.0f / H) - mean * mean;
    float out  = (v - mean) * rsqrtf(var + 1e-5f) * lg[l * H + o] + lb[l * H + o];
    h[(size_t)n * H + o]  = out;
    hb[(size_t)n * H + o] = f2b(out);
}

// ---------- K6: global mean-pool accumulation ----------
__global__ void k_pool(const float* __restrict__ h, const int* __restrict__ batch,
                       float* __restrict__ molsum, float* __restrict__ cnt){
    int idx = blockIdx.x * 256 + threadIdx.x;    // N*H
    int n = idx >> 7, o = idx & 127;
    int b = batch[n];
    atomicAdd(&molsum[b * H + o], h[idx]);
    if (o == 0) atomicAdd(&cnt[b], 1.0f);
}

// ---------- K7: head MLP ----------
__global__ void k_head(const float* __restrict__ molsum, const float* __restrict__ cnt,
                       const float* __restrict__ w1, const float* __restrict__ b1,
                       const float* __restrict__ w2, const float* __restrict__ b2,
                       float* __restrict__ out){
    __shared__ float mol[H];
    int g = blockIdx.x, t = threadIdx.x;   // 64 threads = 1 wave
    float c = fmaxf(cnt[g], 1.0f);
    mol[t]      = molsum[g * H + t] / c;
    mol[t + 64] = molsum[g * H + t + 64] / c;
    __syncthreads();
    float a = b1[t];
    #pragma unroll 8
    for (int i = 0; i < H; ++i) a += mol[i] * w1[i * 64 + t];
    float hid = gelu_exact(a);
    float p = hid * w2[t];
    #pragma unroll
    for (int off = 32; off > 0; off >>= 1) p += __shfl_down(p, off, 64);
    if (t == 0) out[g] = p + b2[0];
}

extern "C" void kernel_launch(void* const* d_in, const int* in_sizes, int n_in,
                              void* d_out, int out_size, void* d_ws, size_t ws_size,
                              hipStream_t stream){
    (void)in_sizes; (void)n_in; (void)out_size; (void)ws_size;
    const float* x     = (const float*)d_in[0];
    const int*   ei    = (const int*)  d_in[1];
    const float* ea    = (const float*)d_in[2];
    const int*   batch = (const int*)  d_in[3];
    const float* aw    = (const float*)d_in[4];
    const float* ab    = (const float*)d_in[5];
    const float* e1w   = (const float*)d_in[6];
    const float* e1b   = (const float*)d_in[7];
    const float* e2w   = (const float*)d_in[8];
    const float* e2b   = (const float*)d_in[9];
    const float* rw    = (const float*)d_in[10];
    const float* cb    = (const float*)d_in[11];
    const float* lg    = (const float*)d_in[12];
    const float* lb    = (const float*)d_in[13];
    const float* hw1   = (const float*)d_in[14];
    const float* hb1   = (const float*)d_in[15];
    const float* hw2   = (const float*)d_in[16];
    const float* hb2   = (const float*)d_in[17];
    float* out = (float*)d_out;

    char* p = (char*)d_ws;
    auto carve = [&](size_t bytes){ char* r = p; p += (bytes + 255) & ~(size_t)255; return r; };
    short* bt     = (short*)carve((size_t)NL * KS * SLICE_SH * 2);    // 12.7 MB
    float* h      = (float*)carve((size_t)N_NODES * H * 4);           // 2 MB
    short* hbuf   = (short*)carve((size_t)N_NODES * H * 2);           // 1 MB
    short* ehT    = (short*)carve((size_t)NL * KS * N_EDGES * 2);     // 6.3 MB
    float* parts  = (float*)carve((size_t)SPLITS * N_EDGES * H * 4);  // 33.5 MB
    int*   ideg   = (int*)  carve((size_t)N_NODES * 4);
    int*   row_ptr= (int*)  carve((size_t)(N_NODES + 1) * 4);
    int*   cursor = (int*)  carve((size_t)N_NODES * 4);
    int*   eidx   = (int*)  carve((size_t)N_EDGES * 4);
    float* molsum = (float*)carve((size_t)NGRAPH * H * 4);
    float* cnt    = (float*)carve((size_t)NGRAPH * 4);

    hipMemsetAsync(ideg, 0, (size_t)N_NODES * 4, stream);
    hipMemsetAsync(molsum, 0, (size_t)NGRAPH * H * 4, stream);
    hipMemsetAsync(cnt, 0, (size_t)NGRAPH * 4, stream);

    k_prep_b<<<NL * KS * 4, 256, 0, stream>>>(e2w, e2b, bt);
    k_atom<<<N_NODES, H, 0, stream>>>(x, aw, ab, h, hbuf);
    k_deg<<<N_EDGES / 256, 256, 0, stream>>>(ei, ideg);
    k_scan<<<1, 256, 0, stream>>>(ideg, row_ptr, cursor);
    k_fill<<<N_EDGES / 256, 256, 0, stream>>>(ei, cursor, eidx);
    k_edge_mlp<<<N_EDGES, H, 0, stream>>>(ea, e1w, e1b, ehT);

    for (int l = 0; l < NL; ++l){
        k_msg_gemm<<<64 * 2 * SPLITS, 256, 0, stream>>>(bt, ehT, hbuf, ei, parts, l);
        k_node<<<N_NODES, H, 0, stream>>>(parts, eidx, row_ptr, rw, cb, lg, lb, h, hbuf, l);
    }
    k_pool<<<N_NODES * H / 256, 256, 0, stream>>>(h, batch, molsum, cnt);
    k_head<<<NGRAPH, 64, 0, stream>>>(molsum, cnt, hw1, hb1, hw2, hb2, out);
}

// Round 6
// 320.129 us; speedup vs baseline: 1.8688x; 1.0352x over previous
//
#include <hip/hip_runtime.h>
#include <hip/hip_bf16.h>

#define N_NODES 4096
#define N_EDGES 8192
#define NGRAPH  256
#define AFEAT   9
#define BFEAT   4
#define H       128
#define NL      3
#define KS      129              // k-slices including the e2_b bias slice
#define SPLITS  4
#define TILE_E  64
#define SLICE_SH    16384        // shorts per k-slice (chunked layout)
#define SLICE_BYTES 32768        // bytes per k-slice
#define WREG_BYTES  8192         // per-wave region: 2 o-tiles x 4 ic x 1KB

typedef short short8 __attribute__((ext_vector_type(8)));
typedef short short4v __attribute__((ext_vector_type(4)));
typedef float f32x4 __attribute__((ext_vector_type(4)));

// ---- bf16 helpers (RNE, finite inputs) ----
__device__ __forceinline__ short f2b(float f){
    union { float f; unsigned u; } c; c.f = f;
    unsigned r = c.u + 0x7FFFu + ((c.u >> 16) & 1u);
    return (short)(r >> 16);
}
__device__ __forceinline__ float b2f(short b){
    union { unsigned u; float f; } c;
    c.u = ((unsigned)(unsigned short)b) << 16;
    return c.f;
}
__device__ __forceinline__ float gelu_exact(float x){
    return 0.5f * x * (1.0f + erff(x * 0.70710678118654752440f));
}
__device__ __forceinline__ void async_copy16(const void* g, void* l){
    typedef __attribute__((address_space(1))) const char AS1C;
    typedef __attribute__((address_space(3))) char AS3;
    __builtin_amdgcn_global_load_lds((AS1C*)g, (AS3*)l, 16, 0, 0);
}

// ---------- K0: e2_w/e2_b -> bt[l][k] in fragment-chunk order ----------
// Element B_k[i][o] stored at short offset
// (((o>>4)*4 + (i>>5))*64 + ((i>>3)&3)*16 + (o&15))*8 + (i&7).
// For fixed (o-tile t, ic): the wave's fragment read is the contiguous
// aligned 1 KB line at byte off (t*4+ic)*1024 + lane*16 (conflict-free;
// measured 0 LDS bank conflicts in round 5). The 8 KB run t in {2w,2w+1}
// is wave-w-exclusive -> barrier-free self-staging in K4.
__global__ void k_prep_b(const float* __restrict__ e2w, const float* __restrict__ e2b,
                         short* __restrict__ bt){
    __shared__ float ts[H][33];
    int b  = blockIdx.x;
    int o0 = (b & 3) * 32;
    int k  = (b >> 2) % KS;
    int l  = (b >> 2) / KS;
    const float* src = (k < H) ? (e2w + ((size_t)l * H + k) * (H * H))
                               : (e2b + (size_t)l * (H * H));
    for (int idx = threadIdx.x; idx < H * 32; idx += 256){
        int i = idx >> 5, op = idx & 31;
        ts[i][op] = src[i * H + o0 + op];
    }
    __syncthreads();
    short* dst = bt + (size_t)(l * KS + k) * SLICE_SH;
    for (int idx = threadIdx.x; idx < 32 * H; idx += 256){
        int j    = idx & 7;
        int quad = (idx >> 3) & 3;
        int op   = (idx >> 5) & 31;
        int ic   = idx >> 10;
        int i    = ic * 32 + quad * 8 + j;
        int o    = o0 + op;
        dst[((((o >> 4) * 4 + ic) * 64) + quad * 16 + (o & 15)) * 8 + j] = f2b(ts[i][op]);
    }
}

// ---------- K1: h0 = relu(x @ atom_w + atom_b) ----------
__global__ void k_atom(const float* __restrict__ x, const float* __restrict__ aw,
                       const float* __restrict__ ab, float* __restrict__ h,
                       short* __restrict__ hb){
    __shared__ float xs[AFEAT];
    int n = blockIdx.x, o = threadIdx.x;
    if (o < AFEAT) xs[o] = x[n * AFEAT + o];
    __syncthreads();
    float a = ab[o];
    #pragma unroll
    for (int f = 0; f < AFEAT; ++f) a += xs[f] * aw[f * H + o];
    a = fmaxf(a, 0.0f);
    h[(size_t)n * H + o]  = a;
    hb[(size_t)n * H + o] = f2b(a);
}

// ---------- K2: in-degree (int histogram) ----------
__global__ void k_deg(const int* __restrict__ ei, int* __restrict__ ideg){
    int e = blockIdx.x * 256 + threadIdx.x;
    if (e < N_EDGES) atomicAdd(&ideg[ei[N_EDGES + e]], 1);
}

// ---------- K2b: exclusive scan -> row_ptr + cursor (one block, once) ----------
__global__ void k_scan(const int* __restrict__ ideg, int* __restrict__ row_ptr,
                       int* __restrict__ cursor){
    __shared__ int part[256];
    int t = threadIdx.x;
    int base = t * 16;
    int loc[16]; int s = 0;
    #pragma unroll
    for (int i = 0; i < 16; ++i){ loc[i] = s; s += ideg[base + i]; }
    part[t] = s;
    __syncthreads();
    if (t == 0){
        int run = 0;
        for (int i = 0; i < 256; ++i){ int v = part[i]; part[i] = run; run += v; }
        row_ptr[N_NODES] = run;
    }
    __syncthreads();
    int off = part[t];
    #pragma unroll
    for (int i = 0; i < 16; ++i){
        row_ptr[base + i] = off + loc[i];
        cursor[base + i]  = off + loc[i];
    }
}

// ---------- K2c: fill CSR edge-id list (once) ----------
__global__ void k_fill(const int* __restrict__ ei, int* __restrict__ cursor,
                       int* __restrict__ eidx){
    int e = blockIdx.x * 256 + threadIdx.x;
    if (e < N_EDGES){
        int d = ei[N_EDGES + e];
        int pos = atomicAdd(&cursor[d], 1);
        eidx[pos] = e;
    }
}

// ---------- K3: eh = gelu(edge_attr @ e1_w + e1_b) for ALL layers, [l][k][e] bf16 ----------
__global__ void k_edge_mlp(const float* __restrict__ ea, const float* __restrict__ w1,
                           const float* __restrict__ b1, short* __restrict__ ehT){
    __shared__ float as[BFEAT];
    int e = blockIdx.x, o = threadIdx.x;
    if (o < BFEAT) as[o] = ea[e * BFEAT + o];
    __syncthreads();
    #pragma unroll
    for (int l = 0; l < NL; ++l){
        float v = b1[l * H + o];
        #pragma unroll
        for (int f = 0; f < BFEAT; ++f) v += as[f] * w1[(l * BFEAT + f) * H + o];
        v = gelu_exact(v);
        ehT[((size_t)l * KS + o) * N_EDGES + e] = f2b(v);
        if (o == 0) ehT[((size_t)l * KS + H) * N_EDGES + e] = f2b(1.0f);   // bias slice
    }
}

// ---------- K4: the big fused GEMM: parts[split][e][o] = sum_k eh[e,k]*(g[e] @ B_k) ----------
// BARRIER-FREE k-loop: block = 64 edges x 128 cols x 1/4 of K, 4 waves.
// Wave w exclusively owns cols [32w,32w+32): it stages its own 8 KB B-region
// (contiguous in bt by construction) with 8 global_load_lds, waits only its
// own vmcnt(8) (1-slice-deep double buffer), reads, MFMAs. No cross-wave
// data flow -> no s_barrier in the loop; wave skew decorrelates stalls.
// LDS 68.1 KB -> 2 blocks/CU; grid 512 = exactly 2 blocks/CU.
__global__ __launch_bounds__(256, 2)
void k_msg_gemm(const short* __restrict__ bt, const short* __restrict__ ehT,
                const short* __restrict__ hb, const int* __restrict__ ei,
                float* __restrict__ parts, int l){
    __shared__ __align__(16) char smem[2 * 4 * WREG_BYTES + 33 * TILE_E * 2];
    short* ehs = (short*)(smem + 2 * 4 * WREG_BYTES);

    const int tid  = threadIdx.x;
    const int lane = tid & 63, w = tid >> 6;   // wave w = o-quarter
    const int col  = lane & 15, quad = lane >> 4;

    const int split = blockIdx.x & 3;
    const int tile  = blockIdx.x >> 2;
    const int kbeg  = (KS * split) >> 2;
    const int kend  = (KS * (split + 1)) >> 2;
    const int kcnt  = kend - kbeg;             // 32 (33 for split 3)
    const int ebase = tile * TILE_E;

    // stage eh slice [kcnt][64] (bf16) once (read-only afterwards)
    for (int idx = tid; idx < kcnt * TILE_E; idx += 256){
        int kk = idx >> 6, e = idx & 63;
        ehs[idx] = ehT[((size_t)(l * KS + kbeg + kk)) * N_EDGES + ebase + e];
    }

    // load G fragments (A-operand, loop-invariant): gf[msub][ichunk]
    short8 gf[4][4];
    #pragma unroll
    for (int m = 0; m < 4; ++m){
        int e = ebase + m * 16 + col;
        int s = ei[e];
        const char* gb = (const char*)hb + ((size_t)s * H + quad * 8) * 2;
        #pragma unroll
        for (int ic = 0; ic < 4; ++ic)
            gf[m][ic] = *(const short8*)(gb + ic * 64);
    }

    float acc[4][2][4];
    #pragma unroll
    for (int m = 0; m < 4; ++m)
        #pragma unroll
        for (int ot = 0; ot < 2; ++ot)
            #pragma unroll
            for (int r = 0; r < 4; ++r) acc[m][ot][r] = 0.0f;

    // this wave's exclusive 8 KB run within each slice of the B stream
    const char* bsrc = (const char*)bt + (size_t)(l * KS + kbeg) * SLICE_BYTES
                     + w * WREG_BYTES;
    char* lws = smem + w * WREG_BYTES;          // buffer p at + p*32768

    // prologue: stage slice 0 into buffer 0 (8 chunk-loads, own region)
    #pragma unroll
    for (int i = 0; i < 8; ++i)
        async_copy16(bsrc + i * 1024 + lane * 16, lws + i * 1024 + lane * 16);

    // one-time: ehs visible to all waves (also drains prologue loads)
    __syncthreads();

    for (int kk = 0; kk < kcnt; ++kk){
        if (kk + 1 < kcnt){
            const char* g = bsrc + (size_t)(kk + 1) * SLICE_BYTES;
            char* d = lws + ((kk + 1) & 1) * (4 * WREG_BYTES);
            // my own reads of buffer d (iter kk-1) are consumed; keep the
            // stage issues ordered after them
            asm volatile("s_waitcnt lgkmcnt(0)" ::: "memory");
            #pragma unroll
            for (int i = 0; i < 8; ++i)
                async_copy16(g + i * 1024 + lane * 16, d + i * 1024 + lane * 16);
            // wait for MY slice-kk loads; slice-(kk+1)'s 8 stay in flight
            asm volatile("s_waitcnt vmcnt(8)" ::: "memory");
        } else {
            asm volatile("s_waitcnt vmcnt(0)" ::: "memory");
        }
        const char* Bl = lws + (kk & 1) * (4 * WREG_BYTES);

        // packed per-row eh scalars (C rows = quad*4+r)
        short4v ev[4];
        #pragma unroll
        for (int m = 0; m < 4; ++m)
            ev[m] = *(const short4v*)(ehs + kk * TILE_E + m * 16 + quad * 4);

        __builtin_amdgcn_s_setprio(1);
        #pragma unroll
        for (int ot = 0; ot < 2; ++ot){
            short8 bf[4];
            #pragma unroll
            for (int ic = 0; ic < 4; ++ic)
                bf[ic] = *(const short8*)(Bl + (ot * 4 + ic) * 1024 + lane * 16);
            #pragma unroll
            for (int m = 0; m < 4; ++m){
                f32x4 U = {0.0f, 0.0f, 0.0f, 0.0f};
                #pragma unroll
                for (int ic = 0; ic < 4; ++ic)
                    U = __builtin_amdgcn_mfma_f32_16x16x32_bf16(gf[m][ic], bf[ic], U, 0, 0, 0);
                #pragma unroll
                for (int r = 0; r < 4; ++r)
                    acc[m][ot][r] += b2f(ev[m][r]) * U[r];
            }
        }
        __builtin_amdgcn_s_setprio(0);
    }

    // epilogue: plain stores of the split-partial (wave-exclusive cols)
    float* pb = parts + (size_t)split * N_EDGES * H + (size_t)ebase * H + w * 32;
    #pragma unroll
    for (int m = 0; m < 4; ++m)
        #pragma unroll
        for (int r = 0; r < 4; ++r){
            float* row = pb + (m * 16 + quad * 4 + r) * H;
            #pragma unroll
            for (int ot = 0; ot < 2; ++ot)
                row[ot * 16 + col] = acc[m][ot][r];
        }
}

// ---------- K5: node update with fused CSR gather over split partials ----------
__global__ void k_node(const float* __restrict__ parts, const int* __restrict__ eidx,
                       const int* __restrict__ row_ptr,
                       const float* __restrict__ rw, const float* __restrict__ cb,
                       const float* __restrict__ lg, const float* __restrict__ lb,
                       float* __restrict__ h, short* __restrict__ hb, int l){
    __shared__ float hs[H];
    __shared__ float rsum[2], rsq[2];
    int n = blockIdx.x, o = threadIdx.x;
    float hv = h[(size_t)n * H + o];
    hs[o] = hv;
    int p0 = row_ptr[n], p1 = row_ptr[n + 1];
    float a = 0.0f;
    for (int p = p0; p < p1; ++p){
        const float* pr = parts + (size_t)eidx[p] * H + o;
        #pragma unroll
        for (int s = 0; s < SPLITS; ++s) a += pr[(size_t)s * N_EDGES * H];
    }
    int d = p1 - p0;
    a *= 1.0f / (float)(d > 0 ? d : 1);
    __syncthreads();
    float root = cb[l * H + o];
    const float* W = rw + (size_t)l * H * H;
    #pragma unroll 8
    for (int i = 0; i < H; ++i) root += hs[i] * W[i * H + o];
    float hn = fmaxf(a + root, 0.0f);
    float v  = hv + hn;
    float s = v, q = v * v;
    #pragma unroll
    for (int off = 32; off > 0; off >>= 1){
        s += __shfl_down(s, off, 64);
        q += __shfl_down(q, off, 64);
    }
    if ((o & 63) == 0){ rsum[o >> 6] = s; rsq[o >> 6] = q; }
    __syncthreads();
    float S = rsum[0] + rsum[1], Q = rsq[0] + rsq[1];
    float mean = S * (1.0f / H);
    float var  = Q * (1.0f / H) - mean * mean;
    float out  = (v - mean) * rsqrtf(var + 1e-5f) * lg[l * H + o] + lb[l * H + o];
    h[(size_t)n * H + o]  = out;
    hb[(size_t)n * H + o] = f2b(out);
}

// ---------- K6: global mean-pool accumulation ----------
__global__ void k_pool(const float* __restrict__ h, const int* __restrict__ batch,
                       float* __restrict__ molsum, float* __restrict__ cnt){
    int idx = blockIdx.x * 256 + threadIdx.x;    // N*H
    int n = idx >> 7, o = idx & 127;
    int b = batch[n];
    atomicAdd(&molsum[b * H + o], h[idx]);
    if (o == 0) atomicAdd(&cnt[b], 1.0f);
}

// ---------- K7: head MLP ----------
__global__ void k_head(const float* __restrict__ molsum, const float* __restrict__ cnt,
                       const float* __restrict__ w1, const float* __restrict__ b1,
                       const float* __restrict__ w2, const float* __restrict__ b2,
                       float* __restrict__ out){
    __shared__ float mol[H];
    int g = blockIdx.x, t = threadIdx.x;   // 64 threads = 1 wave
    float c = fmaxf(cnt[g], 1.0f);
    mol[t]      = molsum[g * H + t] / c;
    mol[t + 64] = molsum[g * H + t + 64] / c;
    __syncthreads();
    float a = b1[t];
    #pragma unroll 8
    for (int i = 0; i < H; ++i) a += mol[i] * w1[i * 64 + t];
    float hid = gelu_exact(a);
    float p = hid * w2[t];
    #pragma unroll
    for (int off = 32; off > 0; off >>= 1) p += __shfl_down(p, off, 64);
    if (t == 0) out[g] = p + b2[0];
}

extern "C" void kernel_launch(void* const* d_in, const int* in_sizes, int n_in,
                              void* d_out, int out_size, void* d_ws, size_t ws_size,
                              hipStream_t stream){
    (void)in_sizes; (void)n_in; (void)out_size; (void)ws_size;
    const float* x     = (const float*)d_in[0];
    const int*   ei    = (const int*)  d_in[1];
    const float* ea    = (const float*)d_in[2];
    const int*   batch = (const int*)  d_in[3];
    const float* aw    = (const float*)d_in[4];
    const float* ab    = (const float*)d_in[5];
    const float* e1w   = (const float*)d_in[6];
    const float* e1b   = (const float*)d_in[7];
    const float* e2w   = (const float*)d_in[8];
    const float* e2b   = (const float*)d_in[9];
    const float* rw    = (const float*)d_in[10];
    const float* cb    = (const float*)d_in[11];
    const float* lg    = (const float*)d_in[12];
    const float* lb    = (const float*)d_in[13];
    const float* hw1   = (const float*)d_in[14];
    const float* hb1   = (const float*)d_in[15];
    const float* hw2   = (const float*)d_in[16];
    const float* hb2   = (const float*)d_in[17];
    float* out = (float*)d_out;

    char* p = (char*)d_ws;
    auto carve = [&](size_t bytes){ char* r = p; p += (bytes + 255) & ~(size_t)255; return r; };
    short* bt     = (short*)carve((size_t)NL * KS * SLICE_SH * 2);    // 12.7 MB
    float* h      = (float*)carve((size_t)N_NODES * H * 4);           // 2 MB
    short* hbuf   = (short*)carve((size_t)N_NODES * H * 2);           // 1 MB
    short* ehT    = (short*)carve((size_t)NL * KS * N_EDGES * 2);     // 6.3 MB
    float* parts  = (float*)carve((size_t)SPLITS * N_EDGES * H * 4);  // 16.7 MB
    int*   ideg   = (int*)  carve((size_t)N_NODES * 4);
    int*   row_ptr= (int*)  carve((size_t)(N_NODES + 1) * 4);
    int*   cursor = (int*)  carve((size_t)N_NODES * 4);
    int*   eidx   = (int*)  carve((size_t)N_EDGES * 4);
    float* molsum = (float*)carve((size_t)NGRAPH * H * 4);
    float* cnt    = (float*)carve((size_t)NGRAPH * 4);

    hipMemsetAsync(ideg, 0, (size_t)N_NODES * 4, stream);
    hipMemsetAsync(molsum, 0, (size_t)NGRAPH * H * 4, stream);
    hipMemsetAsync(cnt, 0, (size_t)NGRAPH * 4, stream);

    k_prep_b<<<NL * KS * 4, 256, 0, stream>>>(e2w, e2b, bt);
    k_atom<<<N_NODES, H, 0, stream>>>(x, aw, ab, h, hbuf);
    k_deg<<<N_EDGES / 256, 256, 0, stream>>>(ei, ideg);
    k_scan<<<1, 256, 0, stream>>>(ideg, row_ptr, cursor);
    k_fill<<<N_EDGES / 256, 256, 0, stream>>>(ei, cursor, eidx);
    k_edge_mlp<<<N_EDGES, H, 0, stream>>>(ea, e1w, e1b, ehT);

    for (int l = 0; l < NL; ++l){
        k_msg_gemm<<<(N_EDGES / TILE_E) * SPLITS, 256, 0, stream>>>(bt, ehT, hbuf, ei, parts, l);
        k_node<<<N_NODES, H, 0, stream>>>(parts, eidx, row_ptr, rw, cb, lg, lb, h, hbuf, l);
    }
    k_pool<<<N_NODES * H / 256, 256, 0, stream>>>(h, batch, molsum, cnt);
    k_head<<<NGRAPH, 64, 0, stream>>>(molsum, cnt, hw1, hb1, hw2, hb2, out);
}